// Round 8
// baseline (194.897 us; speedup 1.0000x reference)
//
#include <hip/hip_runtime.h>
#include <hip/hip_bf16.h>

#define B_ 2
#define S_ 2048
#define D_ 1024
#define H_ 16
#define DK_ 64

typedef __hip_bfloat16 bf16;
typedef short v8s __attribute__((ext_vector_type(8)));
typedef short v4s __attribute__((ext_vector_type(4)));
typedef float v4f __attribute__((ext_vector_type(4)));
typedef float v16f __attribute__((ext_vector_type(16)));
typedef int   v4i __attribute__((ext_vector_type(4)));
typedef int   v2i __attribute__((ext_vector_type(2)));

static __device__ __forceinline__ v16f mfma32(v8s a, v8s b, v16f c) {
  return __builtin_amdgcn_mfma_f32_32x32x16_bf16(a, b, c, 0, 0, 0);
}
static __device__ __forceinline__ void gl2lds16(const void* g, void* l) {
  __builtin_amdgcn_global_load_lds((const __attribute__((address_space(1))) void*)g,
                                   (__attribute__((address_space(3))) void*)l,
                                   16, 0, 0);
}
static __device__ __forceinline__ short f2bf(float x) {  // RNE (pre-passes)
  return (short)__builtin_bit_cast(unsigned short, __float2bfloat16(x));
}
// fast bf16 pair pack: round-half-up then v_perm_b32
static __device__ __forceinline__ int pk2f(float lo, float hi) {
  unsigned a = __builtin_bit_cast(unsigned, lo) + 0x8000u;
  unsigned b = __builtin_bit_cast(unsigned, hi) + 0x8000u;
  return (int)__builtin_amdgcn_perm(b, a, 0x07060302u);
}
static __device__ __forceinline__ float bf2f(short s) {
  return __builtin_bit_cast(float, ((unsigned)(unsigned short)s) << 16);
}

// ---------- merged pre-pass: K->bf16 [bh][s][64] | V->V^T bf16 permuted | Wo->bf16 ----------
__global__ __launch_bounds__(256) void pre_kernel(
    const float* __restrict__ K, const float* __restrict__ V,
    const float* __restrict__ Wo, bf16* __restrict__ Kb,
    bf16* __restrict__ Vt, bf16* __restrict__ Wb)
{
  __shared__ __align__(16) bf16 td[64 * 72];
  const int t = threadIdx.x;
  const int bx = blockIdx.x;

  if (bx < 2048) {           // ---- K: [b][s][h*64+d] -> [bh][s][64]
    const int idx = bx * 256 + t;
    const int seg = idx & 7;
    const int rest = idx >> 3;
    const int h = rest & 15;
    const int bs = rest >> 4;
    const float* src = K + (size_t)bs * D_ + h * 64 + seg * 8;
    v4f x = *(const v4f*)src, y = *(const v4f*)(src + 4);
    v8s r;
    r[0]=f2bf(x[0]); r[1]=f2bf(x[1]); r[2]=f2bf(x[2]); r[3]=f2bf(x[3]);
    r[4]=f2bf(y[0]); r[5]=f2bf(y[1]); r[6]=f2bf(y[2]); r[7]=f2bf(y[3]);
    const int b = bs >> 11, s = bs & 2047;
    *(v8s*)(Kb + ((size_t)(b * H_ + h) * S_ + s) * DK_ + seg * 8) = r;
  } else if (bx < 3072) {    // ---- V -> V^T [bh][64][2048], key-permuted within 32-groups
    const int idx = bx - 2048;
    const int bh = idx >> 5, b = bh >> 4, h = bh & 15;
    const int s0 = (idx & 31) * 64;
    const int srow = t >> 2;
    const int cs = t & 3;
    const float* vp = V + (size_t)(b * S_ + s0 + srow) * D_ + h * 64 + cs * 16;
#pragma unroll
    for (int j = 0; j < 4; j++) {
      v4f x = *(const v4f*)(vp + j * 4);
#pragma unroll
      for (int jj = 0; jj < 4; jj++)
        td[(cs * 16 + j * 4 + jj) * 72 + srow] = __float2bfloat16(x[jj]);
    }
    __syncthreads();
    const int d = t >> 2;
#pragma unroll
    for (int a2 = 0; a2 < 4; a2++) {
      const int pos = cs * 16 + a2 * 4;
      const int g = pos >> 5;
      const int a = (pos >> 2) & 7;
      const int kbase = g * 32 + ((a >> 2) << 4) + ((a & 1) << 3) + (((a >> 1) & 1) << 2);
      v4s val = *(const v4s*)(td + d * 72 + kbase);
      *(v4s*)(Vt + ((size_t)bh * DK_ + d) * S_ + s0 + pos) = val;
    }
  } else {                   // ---- Wo cvt
    const int i = ((bx - 3072) * 256 + t) * 4;
    v4f a = *(const v4f*)(Wo + i);
    v4s r;
    r[0]=f2bf(a[0]); r[1]=f2bf(a[1]); r[2]=f2bf(a[2]); r[3]=f2bf(a[3]);
    *(v4s*)((short*)Wb + i) = r;
  }
}

// ---------- flash attention: 128-thr blocks, 32-key dbuf tiles, key-split x2 ----------
// grid (32 bh, 32 q-tiles of 64, 2 keyhalf); 2 waves x 32 q; 16 KB LDS
__global__ __launch_bounds__(128, 8) void attn5_kernel(
    const float* __restrict__ Q, const bf16* __restrict__ Kb,
    const bf16* __restrict__ Vt, bf16* __restrict__ Op0,
    bf16* __restrict__ Op1, float* __restrict__ Lp)
{
  __shared__ __align__(16) bf16 kk[2][32 * 64];  // 8 KB (aliased by epilogue)
  __shared__ __align__(16) bf16 vv[2][64 * 32];  // 8 KB

  const int t = threadIdx.x;
  const int w = t >> 6, l = t & 63, h2 = l >> 5, ln = l & 31;
  const int bh = blockIdx.x, b = bh >> 4, h = bh & 15;
  const int qbase = blockIdx.y * 64 + w * 32;
  const int z = blockIdx.z;
  const int kb0 = z << 10;

  const bf16* Kbh = Kb + (size_t)bh * (S_ * DK_);
  const bf16* Vbh = Vt + (size_t)bh * (DK_ * S_);

  // Q^T B-frags, scale folded
  const float sc = 0.18033688011112042f;  // (1/sqrt(64)) * log2(e)
  v8s bq[4];
  {
    const float* qp = Q + ((size_t)b * S_ + qbase + ln) * D_ + h * DK_ + h2 * 8;
#pragma unroll
    for (int c = 0; c < 4; c++) {
      v4f x = *(const v4f*)(qp + c * 16);
      v4f y = *(const v4f*)(qp + c * 16 + 4);
      v4i r = { pk2f(x[0]*sc, x[1]*sc), pk2f(x[2]*sc, x[3]*sc),
                pk2f(y[0]*sc, y[1]*sc), pk2f(y[2]*sc, y[3]*sc) };
      bq[c] = __builtin_bit_cast(v8s, r);
    }
  }

  v16f accA, accB;
#pragma unroll
  for (int r = 0; r < 16; r++) { accA[r] = 0.f; accB[r] = 0.f; }
  float lpart = 0.f;

  // prologue: stage tile 0 into buf 0 (2 gl2lds per array per thread)
#pragma unroll
  for (int j = 0; j < 2; j++) {
    const int fk = j * 128 + t, rk = fk >> 3, sk = fk & 7;
    gl2lds16(Kbh + (size_t)(kb0 + rk) * DK_ + ((sk ^ (rk & 7)) * 8), &kk[0][fk * 8]);
    const int fv = j * 128 + t, dv = fv >> 2, sv = fv & 3;
    gl2lds16(Vbh + (size_t)dv * S_ + kb0 + ((sv ^ (dv & 3)) * 8), &vv[0][fv * 8]);
  }

  int it = 0;
  for (int kb = kb0; kb < kb0 + 1024; kb += 32, it ^= 1) {
    __syncthreads();
    if (kb + 32 < kb0 + 1024) {
#pragma unroll
      for (int j = 0; j < 2; j++) {
        const int fk = j * 128 + t, rk = fk >> 3, sk = fk & 7;
        gl2lds16(Kbh + (size_t)(kb + 32 + rk) * DK_ + ((sk ^ (rk & 7)) * 8),
                 &kk[it ^ 1][fk * 8]);
        const int fv = j * 128 + t, dv = fv >> 2, sv = fv & 3;
        gl2lds16(Vbh + (size_t)dv * S_ + (kb + 32) + ((sv ^ (dv & 3)) * 8),
                 &vv[it ^ 1][fv * 8]);
      }
    }
    const bf16* kc_ = kk[it];
    const bf16* vc_ = vv[it];

    v16f s;
#pragma unroll
    for (int r = 0; r < 16; r++) s[r] = 0.f;
#pragma unroll
    for (int c = 0; c < 4; c++) {
      const int sd = 2 * c + h2;
      v8s a0 = *(const v8s*)(kc_ + ln * 64 + ((sd ^ (ln & 7)) * 8));
      s = mfma32(a0, bq[c], s);
    }

    float p[16];
#pragma unroll
    for (int r = 0; r < 16; r++) p[r] = exp2f(s[r]);
    float su = 0.f;
#pragma unroll
    for (int r = 0; r < 16; r++) su += p[r];
    lpart += su;

    v4i i0 = { pk2f(p[0],p[1]),  pk2f(p[2],p[3]),  pk2f(p[4],p[5]),  pk2f(p[6],p[7]) };
    v4i i1 = { pk2f(p[8],p[9]),  pk2f(p[10],p[11]),pk2f(p[12],p[13]),pk2f(p[14],p[15]) };
    v8s pb0 = __builtin_bit_cast(v8s, i0);
    v8s pb1 = __builtin_bit_cast(v8s, i1);

#pragma unroll
    for (int kc = 0; kc < 2; kc++) {
      const int q = kc * 2 + h2;
      v8s avA = *(const v8s*)(vc_ + ln * 32 + ((q ^ (ln & 3)) * 8));
      v8s avB = *(const v8s*)(vc_ + (32 + ln) * 32 + ((q ^ (ln & 3)) * 8));
      v8s pb = kc ? pb1 : pb0;
      accA = mfma32(avA, pb, accA);
      accB = mfma32(avB, pb, accB);
    }
  }

  // epilogue: normalize by partial l, transpose via LDS (aliases kk), store + l
  __syncthreads();
  const float lfull = lpart + __shfl_xor(lpart, 32);
  const float linv = 1.0f / lfull;
  bf16* epw = &kk[0][0] + w * 2048;  // 32 q x 64 d, XOR-swizzled segs
#pragma unroll
  for (int r = 0; r < 16; r += 4) {
    const int off = 4 * h2;
    const int sgA = (r >> 2) ^ (ln & 3);
    const int sgB = 4 + sgA;
    v2i pa = { pk2f(accA[r]*linv,   accA[r+1]*linv),
               pk2f(accA[r+2]*linv, accA[r+3]*linv) };
    v2i pb = { pk2f(accB[r]*linv,   accB[r+1]*linv),
               pk2f(accB[r+2]*linv, accB[r+3]*linv) };
    *(v2i*)(epw + ln * 64 + sgA * 8 + off) = pa;
    *(v2i*)(epw + ln * 64 + sgB * 8 + off) = pb;
  }
  if (h2 == 0)
    Lp[((size_t)z * 32 + bh) * S_ + qbase + ln] = lfull;

  bf16* Op = z ? Op1 : Op0;
  __syncthreads();
#pragma unroll
  for (int i = 0; i < 4; i++) {
    const int flat = i * 64 + l;
    const int qr = flat >> 3, sd = flat & 7;
    const int phys = ((sd & 3) ^ (qr & 3)) | (sd & 4);
    v8s val = *(const v8s*)(epw + qr * 64 + phys * 8);
    *(v8s*)(Op + ((size_t)b * S_ + qbase + qr) * D_ + h * DK_ + sd * 8) = val;
  }
}

// ---------- projection with fused merge: Out = ((l0*o0+l1*o1)/(l0+l1)) @ Wo^T ----------
// 64x64 tile, BK=64, dbuf; A staged via register merge + ds_write; B via gl2lds
__global__ __launch_bounds__(256, 4) void proj4_kernel(
    const bf16* __restrict__ Op0, const bf16* __restrict__ Op1,
    const float* __restrict__ Lp, const bf16* __restrict__ Wo,
    float* __restrict__ Out)
{
  __shared__ __align__(16) bf16 aa[2][64 * 64];
  __shared__ __align__(16) bf16 bb[2][64 * 64];

  const int t = threadIdx.x;
  const int w = t >> 6, l = t & 63, h2 = l >> 5, ln = l & 31;
  const int m0 = blockIdx.x * 64, n0 = blockIdx.y * 64;
  const int wm = (w & 1) * 32, wn = (w >> 1) * 32;

  const int arow = t >> 2;              // 0..63: A row this thread stages
  const int aph = t & 3;                // phys segs {aph, aph+4}
  const int qrow = m0 + arow;
  const int b = qrow >> 11, s = qrow & 2047;

  v16f acc;
#pragma unroll
  for (int r = 0; r < 16; r++) acc[r] = 0.f;

  // ---- staging helpers (macro-ish lambdas) ----
  auto stageA = [&](int k0, int buf) {
    const int h = k0 >> 6;
    const float l0 = Lp[(size_t)(b * H_ + h) * S_ + s];
    const float l1 = Lp[(size_t)(32 + b * H_ + h) * S_ + s];
    const float inv = 1.0f / (l0 + l1);
    const float w0 = l0 * inv, w1 = l1 * inv;
#pragma unroll
    for (int jj = 0; jj < 2; jj++) {
      const int ph = aph + jj * 4;
      const int logical = ph ^ (arow & 7);
      const size_t off = (size_t)qrow * D_ + k0 + logical * 8;
      v8s a8 = *(const v8s*)(Op0 + off);
      v8s c8 = *(const v8s*)(Op1 + off);
      v4i r;
#pragma unroll
      for (int j = 0; j < 4; j++) {
        float lo = w0 * bf2f(a8[2*j])   + w1 * bf2f(c8[2*j]);
        float hi = w0 * bf2f(a8[2*j+1]) + w1 * bf2f(c8[2*j+1]);
        r[j] = pk2f(lo, hi);
      }
      *(v8s*)(&aa[buf][arow * 64 + ph * 8]) = __builtin_bit_cast(v8s, r);
    }
  };
  auto stageB = [&](int k0, int buf) {
#pragma unroll
    for (int j = 0; j < 2; j++) {
      const int flat = j * 256 + t, row = flat >> 3, sp = flat & 7;
      gl2lds16(Wo + (size_t)(n0 + row) * D_ + k0 + ((sp ^ (row & 7)) * 8),
               &bb[buf][flat * 8]);
    }
  };

  stageA(0, 0);
  stageB(0, 0);

  int it = 0;
  for (int k0 = 0; k0 < D_; k0 += 64, it ^= 1) {
    __syncthreads();
    if (k0 + 64 < D_) {
      stageA(k0 + 64, it ^ 1);
      stageB(k0 + 64, it ^ 1);
    }
    const bf16* ac = aa[it];
    const bf16* bc = bb[it];
#pragma unroll
    for (int c = 0; c < 4; c++) {
      const int sd = 2 * c + h2;
      v8s av = *(const v8s*)(ac + (wm + ln) * 64 + ((sd ^ (ln & 7)) * 8));
      v8s bv = *(const v8s*)(bc + (wn + ln) * 64 + ((sd ^ (ln & 7)) * 8));
      acc = mfma32(av, bv, acc);
    }
  }

#pragma unroll
  for (int r = 0; r < 16; r++) {
    const int row = m0 + wm + (r & 3) + 4 * h2 + 8 * (r >> 2);
    Out[(size_t)row * D_ + n0 + wn + ln] = acc[r];
  }
}

extern "C" void kernel_launch(void* const* d_in, const int* in_sizes, int n_in,
                              void* d_out, int out_size, void* d_ws, size_t ws_size,
                              hipStream_t stream) {
  (void)in_sizes; (void)n_in; (void)out_size; (void)ws_size;
  const float* Q  = (const float*)d_in[0];
  const float* K  = (const float*)d_in[1];
  const float* V  = (const float*)d_in[2];
  const float* Wo = (const float*)d_in[3];
  float* out = (float*)d_out;

  bf16* base = (bf16*)d_ws;
  bf16* kb   = base;                               // 8 MB
  bf16* vt   = base + (size_t)4  * 1024 * 1024;    // 8 MB
  bf16* wo_b = base + (size_t)8  * 1024 * 1024;    // 2 MB
  bf16* op0  = base + (size_t)9  * 1024 * 1024;    // 8 MB partial O (keys 0..1023)
  bf16* op1  = base + (size_t)13 * 1024 * 1024;    // 8 MB partial O (keys 1024..2047)
  float* lp  = (float*)(base + (size_t)17 * 1024 * 1024); // 512 KB partial l

  pre_kernel  <<<dim3(4096),       256, 0, stream>>>(K, V, Wo, kb, vt, wo_b);
  attn5_kernel<<<dim3(32, 32, 2),  128, 0, stream>>>(Q, kb, vt, op0, op1, lp);
  proj4_kernel<<<dim3(64, 16),     256, 0, stream>>>(op0, op1, lp, wo_b, out);
}

// Round 9
// 178.127 us; speedup vs baseline: 1.0941x; 1.0941x over previous
//
#include <hip/hip_runtime.h>
#include <hip/hip_bf16.h>

#define B_ 2
#define S_ 2048
#define D_ 1024
#define H_ 16
#define DK_ 64

typedef __hip_bfloat16 bf16;
typedef short v8s __attribute__((ext_vector_type(8)));
typedef short v4s __attribute__((ext_vector_type(4)));
typedef float v4f __attribute__((ext_vector_type(4)));
typedef float v16f __attribute__((ext_vector_type(16)));
typedef int   v4i __attribute__((ext_vector_type(4)));
typedef int   v2i __attribute__((ext_vector_type(2)));

static __device__ __forceinline__ v16f mfma32(v8s a, v8s b, v16f c) {
  return __builtin_amdgcn_mfma_f32_32x32x16_bf16(a, b, c, 0, 0, 0);
}
static __device__ __forceinline__ void gl2lds16(const void* g, void* l) {
  __builtin_amdgcn_global_load_lds((const __attribute__((address_space(1))) void*)g,
                                   (__attribute__((address_space(3))) void*)l,
                                   16, 0, 0);
}
static __device__ __forceinline__ short f2bf(float x) {  // RNE (pre-passes)
  return (short)__builtin_bit_cast(unsigned short, __float2bfloat16(x));
}
// fast bf16 pair pack: round-half-up then v_perm_b32
static __device__ __forceinline__ int pk2f(float lo, float hi) {
  unsigned a = __builtin_bit_cast(unsigned, lo) + 0x8000u;
  unsigned b = __builtin_bit_cast(unsigned, hi) + 0x8000u;
  return (int)__builtin_amdgcn_perm(b, a, 0x07060302u);
}
static __device__ __forceinline__ float bf2f(short s) {
  return __builtin_bit_cast(float, ((unsigned)(unsigned short)s) << 16);
}

// ---------- merged pre-pass: K->bf16 [bh][s][64] | V->V^T bf16 permuted | Wo->bf16 ----------
__global__ __launch_bounds__(256) void pre_kernel(
    const float* __restrict__ K, const float* __restrict__ V,
    const float* __restrict__ Wo, bf16* __restrict__ Kb,
    bf16* __restrict__ Vt, bf16* __restrict__ Wb)
{
  __shared__ __align__(16) bf16 td[64 * 72];
  const int t = threadIdx.x;
  const int bx = blockIdx.x;

  if (bx < 2048) {           // ---- K: [b][s][h*64+d] -> [bh][s][64]
    const int idx = bx * 256 + t;
    const int seg = idx & 7;
    const int rest = idx >> 3;
    const int h = rest & 15;
    const int bs = rest >> 4;
    const float* src = K + (size_t)bs * D_ + h * 64 + seg * 8;
    v4f x = *(const v4f*)src, y = *(const v4f*)(src + 4);
    v8s r;
    r[0]=f2bf(x[0]); r[1]=f2bf(x[1]); r[2]=f2bf(x[2]); r[3]=f2bf(x[3]);
    r[4]=f2bf(y[0]); r[5]=f2bf(y[1]); r[6]=f2bf(y[2]); r[7]=f2bf(y[3]);
    const int b = bs >> 11, s = bs & 2047;
    *(v8s*)(Kb + ((size_t)(b * H_ + h) * S_ + s) * DK_ + seg * 8) = r;
  } else if (bx < 3072) {    // ---- V -> V^T [bh][64][2048], key-permuted within 32-groups
    const int idx = bx - 2048;
    const int bh = idx >> 5, b = bh >> 4, h = bh & 15;
    const int s0 = (idx & 31) * 64;
    const int srow = t >> 2;
    const int cs = t & 3;
    const float* vp = V + (size_t)(b * S_ + s0 + srow) * D_ + h * 64 + cs * 16;
#pragma unroll
    for (int j = 0; j < 4; j++) {
      v4f x = *(const v4f*)(vp + j * 4);
#pragma unroll
      for (int jj = 0; jj < 4; jj++)
        td[(cs * 16 + j * 4 + jj) * 72 + srow] = __float2bfloat16(x[jj]);
    }
    __syncthreads();
    const int d = t >> 2;
#pragma unroll
    for (int a2 = 0; a2 < 4; a2++) {
      const int pos = cs * 16 + a2 * 4;
      const int g = pos >> 5;
      const int a = (pos >> 2) & 7;
      const int kbase = g * 32 + ((a >> 2) << 4) + ((a & 1) << 3) + (((a >> 1) & 1) << 2);
      v4s val = *(const v4s*)(td + d * 72 + kbase);
      *(v4s*)(Vt + ((size_t)bh * DK_ + d) * S_ + s0 + pos) = val;
    }
  } else {                   // ---- Wo cvt
    const int i = ((bx - 3072) * 256 + t) * 4;
    v4f a = *(const v4f*)(Wo + i);
    v4s r;
    r[0]=f2bf(a[0]); r[1]=f2bf(a[1]); r[2]=f2bf(a[2]); r[3]=f2bf(a[3]);
    *(v4s*)((short*)Wb + i) = r;
  }
}

// ---------- flash attention, key-split: grid (32 bh, 16 qtile, 2 keyhalf) ----------
// r7 attn4 verbatim (67 us known-good control)
__global__ __launch_bounds__(256, 4) void attn4_kernel(
    const float* __restrict__ Q, const bf16* __restrict__ Kb,
    const bf16* __restrict__ Vt, bf16* __restrict__ Op0,
    bf16* __restrict__ Op1, float* __restrict__ Lp)
{
  __shared__ __align__(16) bf16 kk[2][64 * 64];
  __shared__ __align__(16) bf16 vv[2][64 * 64];

  const int t = threadIdx.x;
  const int w = t >> 6, l = t & 63, h2 = l >> 5, ln = l & 31;
  const int bh = blockIdx.x, b = bh >> 4, h = bh & 15;
  const int qbase = blockIdx.y * 128 + w * 32;
  const int z = blockIdx.z;
  const int kb0 = z << 10;

  const bf16* Kbh = Kb + (size_t)bh * (S_ * DK_);
  const bf16* Vbh = Vt + (size_t)bh * (DK_ * S_);

  const float sc = 0.18033688011112042f;  // (1/sqrt(64)) * log2(e)
  v8s bq[4];
  {
    const float* qp = Q + ((size_t)b * S_ + qbase + ln) * D_ + h * DK_ + h2 * 8;
#pragma unroll
    for (int c = 0; c < 4; c++) {
      v4f x = *(const v4f*)(qp + c * 16);
      v4f y = *(const v4f*)(qp + c * 16 + 4);
      v4i r = { pk2f(x[0]*sc, x[1]*sc), pk2f(x[2]*sc, x[3]*sc),
                pk2f(y[0]*sc, y[1]*sc), pk2f(y[2]*sc, y[3]*sc) };
      bq[c] = __builtin_bit_cast(v8s, r);
    }
  }

  v16f accA, accB;
#pragma unroll
  for (int r = 0; r < 16; r++) { accA[r] = 0.f; accB[r] = 0.f; }
  float lpart = 0.f;

#pragma unroll
  for (int j = 0; j < 2; j++) {
    const int flat = j * 256 + t, row = flat >> 3, sp = flat & 7;
    gl2lds16(Kbh + (size_t)(kb0 + row) * DK_ + ((sp ^ (row & 7)) * 8), &kk[0][flat * 8]);
    gl2lds16(Vbh + (size_t)row * S_ + kb0 + ((sp ^ (row & 7)) * 8), &vv[0][flat * 8]);
  }

  int it = 0;
  for (int kb = kb0; kb < kb0 + 1024; kb += 64, it ^= 1) {
    __syncthreads();
    if (kb + 64 < kb0 + 1024) {
#pragma unroll
      for (int j = 0; j < 2; j++) {
        const int flat = j * 256 + t, row = flat >> 3, sp = flat & 7;
        gl2lds16(Kbh + (size_t)(kb + 64 + row) * DK_ + ((sp ^ (row & 7)) * 8),
                 &kk[it ^ 1][flat * 8]);
        gl2lds16(Vbh + (size_t)row * S_ + (kb + 64) + ((sp ^ (row & 7)) * 8),
                 &vv[it ^ 1][flat * 8]);
      }
    }
    const bf16* kc_ = kk[it];
    const bf16* vc_ = vv[it];

    v16f s0, s1;
#pragma unroll
    for (int r = 0; r < 16; r++) { s0[r] = 0.f; s1[r] = 0.f; }
#pragma unroll
    for (int c = 0; c < 4; c++) {
      const int sd = 2 * c + h2;
      v8s a0 = *(const v8s*)(kc_ + ln * 64 + ((sd ^ (ln & 7)) * 8));
      v8s a1 = *(const v8s*)(kc_ + (32 + ln) * 64 + ((sd ^ (ln & 7)) * 8));
      s0 = mfma32(a0, bq[c], s0);
      s1 = mfma32(a1, bq[c], s1);
    }

    float p0[16], p1[16];
#pragma unroll
    for (int r = 0; r < 16; r++) { p0[r] = exp2f(s0[r]); p1[r] = exp2f(s1[r]); }
    // 4-partial tree sum (shorter dep chain than serial su)
    float sa = 0.f, sb = 0.f, sc2 = 0.f, sd2 = 0.f;
#pragma unroll
    for (int r = 0; r < 16; r += 4) {
      sa += p0[r];     sb += p0[r + 1];  sc2 += p0[r + 2]; sd2 += p0[r + 3];
      sa += p1[r];     sb += p1[r + 1];  sc2 += p1[r + 2]; sd2 += p1[r + 3];
    }
    lpart += (sa + sb) + (sc2 + sd2);

    v4i i00 = { pk2f(p0[0],p0[1]),  pk2f(p0[2],p0[3]),  pk2f(p0[4],p0[5]),  pk2f(p0[6],p0[7]) };
    v4i i01 = { pk2f(p0[8],p0[9]),  pk2f(p0[10],p0[11]),pk2f(p0[12],p0[13]),pk2f(p0[14],p0[15]) };
    v4i i10 = { pk2f(p1[0],p1[1]),  pk2f(p1[2],p1[3]),  pk2f(p1[4],p1[5]),  pk2f(p1[6],p1[7]) };
    v4i i11 = { pk2f(p1[8],p1[9]),  pk2f(p1[10],p1[11]),pk2f(p1[12],p1[13]),pk2f(p1[14],p1[15]) };
    v8s pb00 = __builtin_bit_cast(v8s, i00);
    v8s pb01 = __builtin_bit_cast(v8s, i01);
    v8s pb10 = __builtin_bit_cast(v8s, i10);
    v8s pb11 = __builtin_bit_cast(v8s, i11);

#pragma unroll
    for (int st = 0; st < 2; st++) {
#pragma unroll
      for (int kc = 0; kc < 2; kc++) {
        const int q = st * 4 + kc * 2 + h2;
        v8s avA = *(const v8s*)(vc_ + ln * 64 + ((q ^ (ln & 7)) * 8));
        v8s avB = *(const v8s*)(vc_ + (32 + ln) * 64 + ((q ^ (ln & 7)) * 8));
        v8s pb = st ? (kc ? pb11 : pb10) : (kc ? pb01 : pb00);
        accA = mfma32(avA, pb, accA);
        accB = mfma32(avB, pb, accB);
      }
    }
  }

  __syncthreads();
  const float lfull = lpart + __shfl_xor(lpart, 32);
  const float linv = 1.0f / lfull;
  bf16* epw = &kk[0][0] + w * 2048;
#pragma unroll
  for (int r = 0; r < 16; r += 4) {
    const int off = 4 * h2;
    const int sgA = (r >> 2) ^ (ln & 3);
    const int sgB = 4 + sgA;
    v2i pa = { pk2f(accA[r]*linv,   accA[r+1]*linv),
               pk2f(accA[r+2]*linv, accA[r+3]*linv) };
    v2i pb = { pk2f(accB[r]*linv,   accB[r+1]*linv),
               pk2f(accB[r+2]*linv, accB[r+3]*linv) };
    *(v2i*)(epw + ln * 64 + sgA * 8 + off) = pa;
    *(v2i*)(epw + ln * 64 + sgB * 8 + off) = pb;
  }
  if (h2 == 0)
    Lp[((size_t)z * 32 + bh) * S_ + qbase + ln] = lfull;

  bf16* Op = z ? Op1 : Op0;
  __syncthreads();
#pragma unroll
  for (int i = 0; i < 4; i++) {
    const int flat = i * 64 + l;
    const int qr = flat >> 3, sd = flat & 7;
    const int phys = ((sd & 3) ^ (qr & 3)) | (sd & 4);
    v8s val = *(const v8s*)(epw + qr * 64 + phys * 8);
    *(v8s*)(Op + ((size_t)b * S_ + qbase - w * 32 + w * 32 + qr) * D_ + h * DK_ + sd * 8) = val;
  }
}

// ---------- merge: o = (l0*o0 + l1*o1)/(l0+l1), bf16 out ----------
__global__ __launch_bounds__(256) void merge_kernel(
    const bf16* __restrict__ Op0, const bf16* __restrict__ Op1,
    const float* __restrict__ Lp, bf16* __restrict__ O)
{
  const int flat = blockIdx.x * 256 + threadIdx.x;
  const int qrow = flat >> 7;
  const int seg = flat & 127;
  const int b = qrow >> 11, s = qrow & 2047;
  const int h = seg >> 3;
  const int bh = b * H_ + h;
  const float l0 = Lp[(size_t)bh * S_ + s];
  const float l1 = Lp[(size_t)(32 + bh) * S_ + s];
  const float inv = 1.0f / (l0 + l1);
  const float w0 = l0 * inv, w1 = l1 * inv;
  const size_t off = (size_t)qrow * D_ + seg * 8;
  v8s a = *(const v8s*)(Op0 + off);
  v8s c = *(const v8s*)(Op1 + off);
  v4i r;
#pragma unroll
  for (int j = 0; j < 4; j++) {
    float lo = w0 * bf2f(a[2*j])   + w1 * bf2f(c[2*j]);
    float hi = w0 * bf2f(a[2*j+1]) + w1 * bf2f(c[2*j+1]);
    r[j] = pk2f(lo, hi);
  }
  *(v8s*)(O + off) = __builtin_bit_cast(v8s, r);
}

// ---------- projection: 128x128 tile, BK=64, mfma32, dbuf, grid (32,8)=256 ----------
// wave = 64x64 out (2x2 of 32x32); 16 MFMAs per 16 ds_read_b128 per step
__global__ __launch_bounds__(256, 2) void proj6_kernel(
    const bf16* __restrict__ A, const bf16* __restrict__ Wo, float* __restrict__ Out)
{
  __shared__ __align__(16) bf16 aa[2][128 * 64];  // 16 KB each
  __shared__ __align__(16) bf16 bb[2][128 * 64];

  const int t = threadIdx.x;
  const int w = t >> 6, l = t & 63, h2 = l >> 5, ln = l & 31;
  const int m0 = blockIdx.x * 128, n0 = blockIdx.y * 128;
  const int wm = (w & 1) * 64, wn = (w >> 1) * 64;

  v16f acc[2][2];
#pragma unroll
  for (int mi = 0; mi < 2; mi++)
#pragma unroll
    for (int ni = 0; ni < 2; ni++)
#pragma unroll
      for (int r = 0; r < 16; r++) acc[mi][ni][r] = 0.f;

  // staging: 128 rows x 64 k each for A and B; 4 gl2lds per thread per array
#pragma unroll
  for (int j = 0; j < 4; j++) {
    const int flat = j * 256 + t, row = flat >> 3, sp = flat & 7;
    gl2lds16(A  + (size_t)(m0 + row) * D_ + ((sp ^ (row & 7)) * 8), &aa[0][flat * 8]);
    gl2lds16(Wo + (size_t)(n0 + row) * D_ + ((sp ^ (row & 7)) * 8), &bb[0][flat * 8]);
  }

  int it = 0;
  for (int k0 = 0; k0 < D_; k0 += 64, it ^= 1) {
    __syncthreads();
    if (k0 + 64 < D_) {
#pragma unroll
      for (int j = 0; j < 4; j++) {
        const int flat = j * 256 + t, row = flat >> 3, sp = flat & 7;
        gl2lds16(A  + (size_t)(m0 + row) * D_ + (k0 + 64) + ((sp ^ (row & 7)) * 8),
                 &aa[it ^ 1][flat * 8]);
        gl2lds16(Wo + (size_t)(n0 + row) * D_ + (k0 + 64) + ((sp ^ (row & 7)) * 8),
                 &bb[it ^ 1][flat * 8]);
      }
    }
    const bf16* ac = aa[it];
    const bf16* bc = bb[it];
#pragma unroll
    for (int kc = 0; kc < 4; kc++) {
      const int sd = 2 * kc + h2;   // logical seg for k = kc*16 + h2*8
      v8s am[2], bn[2];
#pragma unroll
      for (int mi = 0; mi < 2; mi++)
        am[mi] = *(const v8s*)(ac + (wm + mi * 32 + ln) * 64 + ((sd ^ (ln & 7)) * 8));
#pragma unroll
      for (int ni = 0; ni < 2; ni++)
        bn[ni] = *(const v8s*)(bc + (wn + ni * 32 + ln) * 64 + ((sd ^ (ln & 7)) * 8));
#pragma unroll
      for (int mi = 0; mi < 2; mi++)
#pragma unroll
        for (int ni = 0; ni < 2; ni++)
          acc[mi][ni] = mfma32(am[mi], bn[ni], acc[mi][ni]);
    }
  }

  // C layout: col n = ln, row m = (r&3) + 4*h2 + 8*(r>>2)
#pragma unroll
  for (int mi = 0; mi < 2; mi++)
#pragma unroll
    for (int ni = 0; ni < 2; ni++)
#pragma unroll
      for (int r = 0; r < 16; r++) {
        const int row = m0 + wm + mi * 32 + (r & 3) + 4 * h2 + 8 * (r >> 2);
        Out[(size_t)row * D_ + n0 + wn + ni * 32 + ln] = acc[mi][ni][r];
      }
}

extern "C" void kernel_launch(void* const* d_in, const int* in_sizes, int n_in,
                              void* d_out, int out_size, void* d_ws, size_t ws_size,
                              hipStream_t stream) {
  (void)in_sizes; (void)n_in; (void)out_size; (void)ws_size;
  const float* Q  = (const float*)d_in[0];
  const float* K  = (const float*)d_in[1];
  const float* V  = (const float*)d_in[2];
  const float* Wo = (const float*)d_in[3];
  float* out = (float*)d_out;

  bf16* base = (bf16*)d_ws;
  bf16* kb   = base;                               // 8 MB (reused as merged-o)
  bf16* vt   = base + (size_t)4  * 1024 * 1024;    // 8 MB
  bf16* wo_b = base + (size_t)8  * 1024 * 1024;    // 2 MB
  bf16* op0  = base + (size_t)9  * 1024 * 1024;    // 8 MB partial O (keys 0..1023)
  bf16* op1  = base + (size_t)13 * 1024 * 1024;    // 8 MB partial O (keys 1024..2047)
  float* lp  = (float*)(base + (size_t)17 * 1024 * 1024); // 512 KB partial l
  bf16* ows  = kb;

  pre_kernel  <<<dim3(4096),       256, 0, stream>>>(K, V, Wo, kb, vt, wo_b);
  attn4_kernel<<<dim3(32, 16, 2),  256, 0, stream>>>(Q, kb, vt, op0, op1, lp);
  merge_kernel<<<dim3(2048),       256, 0, stream>>>(op0, op1, lp, ows);
  proj6_kernel<<<dim3(32, 8),      256, 0, stream>>>(ows, wo_b, out);
}